// Round 2
// baseline (71.957 us; speedup 1.0000x reference)
//
#include <hip/hip_runtime.h>

// ROI Align forward, fp32. Shapes fixed by the reference:
//   input: (N=4, C=256, H=200, W=200) f32
//   rois:  (M=1024, 5) f32   [batch_idx, x1, y1, x2, y2]
//   out:   (M, C, 7, 7) f32
// One thread per output element; linear idx == output flat idx -> coalesced
// stores. Gathers hit a small per-ROI footprint; input (164 MB) is L3-resident.

#define OUT_H 7
#define OUT_W 7
#define SPATIAL_SCALE 0.25f

__global__ __launch_bounds__(256) void roi_align_fwd(
        const float* __restrict__ inp,
        const float* __restrict__ rois,
        float* __restrict__ out,
        int C, int H, int W, int total) {
    int idx = blockIdx.x * blockDim.x + threadIdx.x;
    if (idx >= total) return;

    const int pw = idx % OUT_W;
    const int ph = (idx / OUT_W) % OUT_H;
    const int c  = (idx / (OUT_W * OUT_H)) % C;
    const int m  = idx / (OUT_W * OUT_H * C);

    // ROI params (wave-uniform per m; L1-broadcast)
    const float* r = rois + (size_t)m * 5;
    const int   b  = (int)r[0];
    const float x1 = r[1] * SPATIAL_SCALE;
    const float y1 = r[2] * SPATIAL_SCALE;
    const float x2 = r[3] * SPATIAL_SCALE;
    const float y2 = r[4] * SPATIAL_SCALE;

    const float roi_w = fmaxf(x2 - x1, 1.0f);
    const float roi_h = fmaxf(y2 - y1, 1.0f);
    const float bin_w = roi_w * (1.0f / OUT_W);
    const float bin_h = roi_h * (1.0f / OUT_H);

    const float y_s = y1 + ((float)ph + 0.5f) * bin_h;
    const float x_s = x1 + ((float)pw + 0.5f) * bin_w;
    const float py  = y_s * ((float)(H - 1) / (float)H);
    const float px  = x_s * ((float)(W - 1) / (float)W);

    const float fy = floorf(py);
    const float fx = floorf(px);
    const int y0 = (int)fy;
    const int x0 = (int)fx;
    const float ly = py - fy;
    const float lx = px - fx;

    const float* __restrict__ base = inp + ((size_t)b * C + c) * (size_t)(H * W);

    // 4-corner gather with the reference's validity semantics
    float v[4];
    int yy[2] = { y0, y0 + 1 };
    int xx[2] = { x0, x0 + 1 };
#pragma unroll
    for (int j = 0; j < 2; ++j) {
#pragma unroll
        for (int i = 0; i < 2; ++i) {
            const int yc = yy[j], xc = xx[i];
            const bool valid = (yc >= 0) & (yc < H) & (xc >= 0) & (xc < W);
            const int ycl = min(max(yc, 0), H - 1);
            const int xcl = min(max(xc, 0), W - 1);
            const float val = base[(size_t)ycl * W + xcl];
            v[j * 2 + i] = valid ? val : 0.0f;
        }
    }

    const float w00 = (1.0f - ly) * (1.0f - lx);
    const float w01 = (1.0f - ly) * lx;
    const float w10 = ly * (1.0f - lx);
    const float w11 = ly * lx;

    out[idx] = w00 * v[0] + w01 * v[1] + w10 * v[2] + w11 * v[3];
}

extern "C" void kernel_launch(void* const* d_in, const int* in_sizes, int n_in,
                              void* d_out, int out_size, void* d_ws, size_t ws_size,
                              hipStream_t stream) {
    const float* inp  = (const float*)d_in[0];
    const float* rois = (const float*)d_in[1];
    float* out = (float*)d_out;

    const int C = 256, H = 200, W = 200;
    const int total = out_size;  // M * C * 7 * 7

    const int block = 256;
    const int grid = (total + block - 1) / block;
    roi_align_fwd<<<grid, block, 0, stream>>>(inp, rois, out, C, H, W, total);
}

// Round 3
// 70.897 us; speedup vs baseline: 1.0150x; 1.0150x over previous
//
#include <hip/hip_runtime.h>

// ROI Align forward, fp32. Shapes fixed by the reference:
//   input: (N=4, C=256, H=200, W=200) f32
//   rois:  (M=1024, 5) f32   [batch_idx, x1, y1, x2, y2]
//   out:   (M, C, 7, 7) f32
//
// Block-per-ROI-segment design:
//   - 12544 outputs per ROI = 7 segments x (7 iters x 256 threads)
//   - threads 0..48 precompute per-bin clamped corner offsets + validity-
//     folded bilinear weights into LDS once per block
//   - inner loop: magic-div by 49, 2x ds_read_b128, 4 gathers, 3 fma,
//     1 perfectly-coalesced store. 28 loads in flight per thread.

#define OUT_H 7
#define OUT_W 7
#define NPOS 49                  // OUT_H * OUT_W
#define SPATIAL_SCALE 0.25f
#define BLOCK 256
#define ITERS 7
#define SPLIT 7                  // blocks per ROI; SPLIT*ITERS*BLOCK = C*49

__global__ __launch_bounds__(BLOCK) void roi_align_fwd(
        const float* __restrict__ inp,
        const float* __restrict__ rois,
        float* __restrict__ out,
        int C, int H, int W) {
    const int blk = blockIdx.x;
    const int m   = blk / SPLIT;
    const int seg = blk % SPLIT;

    __shared__ int4   s_idx[NPOS];   // {y0c*W, y1c*W, x0c, x1c}
    __shared__ float4 s_w[NPOS];     // validity-folded bilinear weights

    const float* __restrict__ r = rois + (size_t)m * 5;

    if (threadIdx.x < NPOS) {
        const int pos = threadIdx.x;
        const int ph = pos / OUT_W;
        const int pw = pos % OUT_W;

        const float x1 = r[1] * SPATIAL_SCALE;
        const float y1 = r[2] * SPATIAL_SCALE;
        const float x2 = r[3] * SPATIAL_SCALE;
        const float y2 = r[4] * SPATIAL_SCALE;

        const float roi_w = fmaxf(x2 - x1, 1.0f);
        const float roi_h = fmaxf(y2 - y1, 1.0f);
        const float bin_w = roi_w * (1.0f / OUT_W);
        const float bin_h = roi_h * (1.0f / OUT_H);

        const float y_s = y1 + ((float)ph + 0.5f) * bin_h;
        const float x_s = x1 + ((float)pw + 0.5f) * bin_w;
        const float py  = y_s * ((float)(H - 1) / (float)H);
        const float px  = x_s * ((float)(W - 1) / (float)W);

        const float fy = floorf(py);
        const float fx = floorf(px);
        const int y0 = (int)fy;
        const int x0 = (int)fx;
        const float ly = py - fy;
        const float lx = px - fx;

        const int y1i = y0 + 1;
        const int x1i = x0 + 1;

        const bool vy0 = (y0  >= 0) & (y0  < H);
        const bool vy1 = (y1i >= 0) & (y1i < H);
        const bool vx0 = (x0  >= 0) & (x0  < W);
        const bool vx1 = (x1i >= 0) & (x1i < W);

        const int y0c = min(max(y0,  0), H - 1);
        const int y1c = min(max(y1i, 0), H - 1);
        const int x0c = min(max(x0,  0), W - 1);
        const int x1c = min(max(x1i, 0), W - 1);

        float w00 = (1.0f - ly) * (1.0f - lx);
        float w01 = (1.0f - ly) * lx;
        float w10 = ly * (1.0f - lx);
        float w11 = ly * lx;
        w00 = (vy0 & vx0) ? w00 : 0.0f;
        w01 = (vy0 & vx1) ? w01 : 0.0f;
        w10 = (vy1 & vx0) ? w10 : 0.0f;
        w11 = (vy1 & vx1) ? w11 : 0.0f;

        s_idx[pos] = make_int4(y0c * W, y1c * W, x0c, x1c);
        s_w[pos]   = make_float4(w00, w01, w10, w11);
    }

    const int b = (int)r[0];   // uniform per block
    __syncthreads();

    const float* __restrict__ base_n = inp + (size_t)b * C * (size_t)(H * W);
    float* __restrict__ outm = out + (size_t)m * (size_t)(C * NPOS);
    const int segbase = seg * (BLOCK * ITERS);

#pragma unroll
    for (int it = 0; it < ITERS; ++it) {
        const int sub = segbase + it * BLOCK + (int)threadIdx.x;   // < C*49
        const int c   = sub / NPOS;          // magic-mul divide by 49
        const int pos = sub - c * NPOS;

        const float* __restrict__ base = base_n + (size_t)c * (size_t)(H * W);
        const int4   ix = s_idx[pos];
        const float4 w  = s_w[pos];

        const float v00 = base[ix.x + ix.z];
        const float v01 = base[ix.x + ix.w];
        const float v10 = base[ix.y + ix.z];
        const float v11 = base[ix.y + ix.w];

        outm[sub] = w.x * v00 + w.y * v01 + w.z * v10 + w.w * v11;
    }
}

extern "C" void kernel_launch(void* const* d_in, const int* in_sizes, int n_in,
                              void* d_out, int out_size, void* d_ws, size_t ws_size,
                              hipStream_t stream) {
    const float* inp  = (const float*)d_in[0];
    const float* rois = (const float*)d_in[1];
    float* out = (float*)d_out;

    const int C = 256, H = 200, W = 200;
    const int M = in_sizes[1] / 5;           // 1024

    const int grid = M * SPLIT;              // 7168 blocks
    roi_align_fwd<<<grid, BLOCK, 0, stream>>>(inp, rois, out, C, H, W);
}

// Round 4
// 70.248 us; speedup vs baseline: 1.0243x; 1.0092x over previous
//
#include <hip/hip_runtime.h>

// ROI Align forward, fp32. Fixed shapes:
//   input: (N=4, C=256, H=200, W=200) f32
//   rois:  (M=1024, 5) f32   [batch_idx, x1, y1, x2, y2]
//   out:   (M, C, 7, 7) f32
//
// Position-resident design:
//   - block = (ROI, half-of-channels); 4 waves x 64 lanes
//   - lane = bin position (0..48; 49..63 exec-masked off -- their lanes
//     issue no loads/stores, and VALU runs at wave rate regardless)
//   - per-lane corner offsets (incl. b*C*HW) + folded weights hoisted to
//     registers once from LDS
//   - channel loop: 4 pointer bumps by constant stride, 4 gathers, 4 FMA,
//     1 coalesced store. unroll 4 -> 16 gathers in flight.

#define OUT_H 7
#define OUT_W 7
#define NPOS 49
#define SPATIAL_SCALE 0.25f
#define BLOCK 256
#define C_CONST 256
#define H_CONST 200
#define W_CONST 200
#define HW_CONST (H_CONST * W_CONST)
#define SPLITC 2                    // blocks per ROI
#define CH_PER_WAVE (C_CONST / SPLITC / 4)   // 32 channels per wave

__global__ __launch_bounds__(BLOCK) void roi_align_fwd(
        const float* __restrict__ inp,
        const float* __restrict__ rois,
        float* __restrict__ out) {
    const int m   = blockIdx.x >> 1;
    const int seg = blockIdx.x & 1;

    __shared__ int4   s_off[NPOS];   // 4 corner element offsets (incl. b*C*HW)
    __shared__ float4 s_w[NPOS];     // validity-folded bilinear weights

    const float* __restrict__ r = rois + (size_t)m * 5;

    if (threadIdx.x < NPOS) {
        const int pos = threadIdx.x;
        const int ph = pos / OUT_W;
        const int pw = pos % OUT_W;

        const int   b  = (int)r[0];
        const float x1 = r[1] * SPATIAL_SCALE;
        const float y1 = r[2] * SPATIAL_SCALE;
        const float x2 = r[3] * SPATIAL_SCALE;
        const float y2 = r[4] * SPATIAL_SCALE;

        const float roi_w = fmaxf(x2 - x1, 1.0f);
        const float roi_h = fmaxf(y2 - y1, 1.0f);
        const float bin_w = roi_w * (1.0f / OUT_W);
        const float bin_h = roi_h * (1.0f / OUT_H);

        const float y_s = y1 + ((float)ph + 0.5f) * bin_h;
        const float x_s = x1 + ((float)pw + 0.5f) * bin_w;
        const float py  = y_s * ((float)(H_CONST - 1) / (float)H_CONST);
        const float px  = x_s * ((float)(W_CONST - 1) / (float)W_CONST);

        const float fy = floorf(py);
        const float fx = floorf(px);
        const int y0 = (int)fy;
        const int x0 = (int)fx;
        const float ly = py - fy;
        const float lx = px - fx;

        const int y1i = y0 + 1;
        const int x1i = x0 + 1;

        const bool vy0 = (y0  >= 0) & (y0  < H_CONST);
        const bool vy1 = (y1i >= 0) & (y1i < H_CONST);
        const bool vx0 = (x0  >= 0) & (x0  < W_CONST);
        const bool vx1 = (x1i >= 0) & (x1i < W_CONST);

        const int y0c = min(max(y0,  0), H_CONST - 1);
        const int y1c = min(max(y1i, 0), H_CONST - 1);
        const int x0c = min(max(x0,  0), W_CONST - 1);
        const int x1c = min(max(x1i, 0), W_CONST - 1);

        float w00 = (1.0f - ly) * (1.0f - lx);
        float w01 = (1.0f - ly) * lx;
        float w10 = ly * (1.0f - lx);
        float w11 = ly * lx;
        w00 = (vy0 & vx0) ? w00 : 0.0f;
        w01 = (vy0 & vx1) ? w01 : 0.0f;
        w10 = (vy1 & vx0) ? w10 : 0.0f;
        w11 = (vy1 & vx1) ? w11 : 0.0f;

        const int nb = b * (C_CONST * HW_CONST);
        s_off[pos] = make_int4(nb + y0c * W_CONST + x0c,
                               nb + y0c * W_CONST + x1c,
                               nb + y1c * W_CONST + x0c,
                               nb + y1c * W_CONST + x1c);
        s_w[pos]   = make_float4(w00, w01, w10, w11);
    }
    __syncthreads();

    const int lane = threadIdx.x & 63;
    const int wid  = threadIdx.x >> 6;          // 0..3

    if (lane < NPOS) {
        const int pos = lane;
        const int4   off = s_off[pos];
        const float4 w   = s_w[pos];
        const int c0 = seg * (C_CONST / SPLITC) + wid;   // wave's first channel

        const int cbase = c0 * HW_CONST;
        const float* p00 = inp + (size_t)(unsigned)(off.x + cbase);
        const float* p01 = inp + (size_t)(unsigned)(off.y + cbase);
        const float* p10 = inp + (size_t)(unsigned)(off.z + cbase);
        const float* p11 = inp + (size_t)(unsigned)(off.w + cbase);

        float* po = out + (size_t)m * (C_CONST * NPOS)
                        + (size_t)c0 * NPOS + pos;

        const int cstep = 4 * HW_CONST;   // 4 channels per iteration (per wave)
#pragma unroll 4
        for (int k = 0; k < CH_PER_WAVE; ++k) {
            const float v00 = *p00;
            const float v01 = *p01;
            const float v10 = *p10;
            const float v11 = *p11;
            *po = w.x * v00 + w.y * v01 + w.z * v10 + w.w * v11;
            p00 += cstep; p01 += cstep; p10 += cstep; p11 += cstep;
            po  += 4 * NPOS;
        }
    }
}

extern "C" void kernel_launch(void* const* d_in, const int* in_sizes, int n_in,
                              void* d_out, int out_size, void* d_ws, size_t ws_size,
                              hipStream_t stream) {
    const float* inp  = (const float*)d_in[0];
    const float* rois = (const float*)d_in[1];
    float* out = (float*)d_out;

    const int M = in_sizes[1] / 5;            // 1024
    const int grid = M * SPLITC;              // 2048 blocks = 32 waves/CU

    roi_align_fwd<<<grid, BLOCK, 0, stream>>>(inp, rois, out);
}